// Round 15
// baseline (699.850 us; speedup 1.0000x reference)
//
#include <hip/hip_runtime.h>

using u16 = unsigned short;
using u32 = unsigned int;

typedef short bfrag8 __attribute__((ext_vector_type(8)));   // 8 x bf16
typedef float f32x4  __attribute__((ext_vector_type(4)));

__device__ __forceinline__ void unpack8(const int4 v, float f[8]) {
  u32 a = (u32)v.x, b = (u32)v.y, c = (u32)v.z, d = (u32)v.w;
  f[0] = __uint_as_float(a << 16);
  f[1] = __uint_as_float(a & 0xffff0000u);
  f[2] = __uint_as_float(b << 16);
  f[3] = __uint_as_float(b & 0xffff0000u);
  f[4] = __uint_as_float(c << 16);
  f[5] = __uint_as_float(c & 0xffff0000u);
  f[6] = __uint_as_float(d << 16);
  f[7] = __uint_as_float(d & 0xffff0000u);
}

__device__ __forceinline__ u16 f2bf(float f) {
  u32 u = __float_as_uint(f);
  u32 r = u + 0x7fffu + ((u >> 16) & 1u);
  return (u16)(r >> 16);
}

__device__ __forceinline__ void gload_lds16(const void* g, void* l) {
  __builtin_amdgcn_global_load_lds(
      (const __attribute__((address_space(1))) void*)g,
      (__attribute__((address_space(3))) void*)l, 16, 0, 0);
}

// ---------------------------------------------------------------------------
// Weight prep: fp32 OIHW [256][256][3][3] -> bf16 [9 tap][256 oc][256 ic]
// ---------------------------------------------------------------------------
__global__ __launch_bounds__(256) void wprep(
    const float* __restrict__ wq, const float* __restrict__ wk, const float* __restrict__ wo,
    u16* __restrict__ dq, u16* __restrict__ dk, u16* __restrict__ dwo)
{
  const float* s = (blockIdx.y == 0) ? wq : (blockIdx.y == 1) ? wk : wo;
  u16* d = (blockIdx.y == 0) ? dq : (blockIdx.y == 1) ? dk : dwo;
  int id = blockIdx.x * 256 + threadIdx.x;
  int e = id * 4;                 // output element base: [tap][oc][ic]
  int tap = e >> 16;
  int rem = e & 65535;
  int oc = rem >> 8, ic = rem & 255;
  u16 o[4];
#pragma unroll
  for (int j = 0; j < 4; ++j)
    o[j] = f2bf(s[((size_t)oc * 256 + ic + j) * 9 + tap]);
  *reinterpret_cast<uint2*>(d + e) = *reinterpret_cast<uint2*>(o);
}

// ---------------------------------------------------------------------------
// Transpose-convert: fp32 NCHW -> bf16 NHWC.
// ---------------------------------------------------------------------------
__global__ __launch_bounds__(256) void xpose(
    const float* __restrict__ xa, const float* __restrict__ xb,
    u16* __restrict__ oa, u16* __restrict__ ob)
{
  const int row = blockIdx.x, b = blockIdx.y;
  const float* src = blockIdx.z ? xb : xa;
  u16* dst = blockIdx.z ? ob : oa;
  const int t = threadIdx.x;
  const int px4 = (t >> 3) * 4;     // 0..124
  const int c8 = (t & 7) * 8;       // 0..56
#pragma unroll
  for (int p = 0; p < 4; ++p) {
    int c0 = p * 64 + c8;
    float4 v[8];
#pragma unroll
    for (int j = 0; j < 8; ++j)
      v[j] = *reinterpret_cast<const float4*>(src + ((size_t)b * 256 + c0 + j) * 16384 + row * 128 + px4);
#pragma unroll
    for (int e = 0; e < 4; ++e) {
      u16 o[8];
      o[0] = f2bf(e==0?v[0].x:e==1?v[0].y:e==2?v[0].z:v[0].w);
      o[1] = f2bf(e==0?v[1].x:e==1?v[1].y:e==2?v[1].z:v[1].w);
      o[2] = f2bf(e==0?v[2].x:e==1?v[2].y:e==2?v[2].z:v[2].w);
      o[3] = f2bf(e==0?v[3].x:e==1?v[3].y:e==2?v[3].z:v[3].w);
      o[4] = f2bf(e==0?v[4].x:e==1?v[4].y:e==2?v[4].z:v[4].w);
      o[5] = f2bf(e==0?v[5].x:e==1?v[5].y:e==2?v[5].z:v[5].w);
      o[6] = f2bf(e==0?v[6].x:e==1?v[6].y:e==2?v[6].z:v[6].w);
      o[7] = f2bf(e==0?v[7].x:e==1?v[7].y:e==2?v[7].z:v[7].w);
      *reinterpret_cast<int4*>(dst + (((size_t)b * 128 + row) * 128 + px4 + e) * 256 + c0) =
          *reinterpret_cast<int4*>(o);
    }
  }
}

// ---------------------------------------------------------------------------
// Implicit-GEMM bf16 MFMA conv3x3 — R15: R14's 40960B LDS diet (4 blocks/CU,
// zero-tail grid) with the SYNC RACE FIXED: each wave drains its own stage-A
// loads (vmcnt(0)) BEFORE the tap barrier, so the barrier certifies all
// waves' LDS writes have landed (R6/R9/R11 invariant).
// ---------------------------------------------------------------------------
__global__ __launch_bounds__(256, 4) void conv_mfma(
    const u16* __restrict__ X, const u16* __restrict__ W2, u16* __restrict__ Y,
    float* __restrict__ part, u16* __restrict__ kTout)
{
  __shared__ __attribute__((aligned(16))) char csm[40960];
  // B plane p @ p*8192 : [128 px][4 q][16B]. A @ 24576 : 2 x 8192.
  // epilogue alias: Ost [128][136]u16 (34816) + sst 512 f32 @34816 (2048)

  const int t = threadIdx.x;
  const int l = t & 63;
  const int wv = t >> 6;
  const int id = blockIdx.x;
  const int u = (id & 7) * 256 + (id >> 3);   // XCD-chunk swizzle (bijective, 2048)
  const int bb = u >> 8;
  const int y0 = (u >> 1) & 127;
  const int ocblk = u & 1;
  const int oc0 = ocblk * 128;
  const int och = wv >> 1, pxh = wv & 1;
  const int lc = l & 15, lq = l >> 4;
  const int sa = (lc >> 1) & 3;

  f32x4 acc[4][4];
#pragma unroll
  for (int m = 0; m < 4; ++m)
#pragma unroll
    for (int n = 0; n < 4; ++n) acc[m][n] = (f32x4){0.f, 0.f, 0.f, 0.f};

  const size_t xplane = (size_t)bb * (128 * 128 * 256);

  // prologue zeros: OOB kh planes only (halo cols handled in registers)
  {
    int4 z = {0, 0, 0, 0};
    if (y0 == 0)
      for (int s = t; s < 512; s += 256) reinterpret_cast<int4*>(csm)[s] = z;
    if (y0 == 127)
      for (int s = t; s < 512; s += 256) reinterpret_cast<int4*>(csm + 16384)[s] = z;
  }

  // A stage: 128 oc x 32 ic per tap. slot (oc,q) holds octet q ^ ((oc>>1)&3)
  auto stageA = [&](int tap, int buf, int ic0) {
#pragma unroll
    for (int i = 0; i < 2; ++i) {
      int idx = t + i * 256;
      int oc = idx >> 2, q = idx & 3;
      int qs = q ^ ((oc >> 1) & 3);
      const u16* src = W2 + (((size_t)(tap * 256 + oc0 + oc)) << 8) + ic0 + qs * 8;
      gload_lds16(src, csm + 24576 + buf * 8192 + (i * 256 + (t & ~63)) * 16);
    }
  };
  // B stage: plane kh, col=px, slot q holds octet q ^ ((px>>1)&3)
  auto stageB = [&](int ic0) {
#pragma unroll
    for (int i = 0; i < 6; ++i) {
      int idx = t + i * 256;
      int kh = idx >> 9;
      int row = y0 - 1 + kh;
      if (row >= 0 && row < 128) {
        int inner = idx & 511;
        int px = inner >> 2, q = inner & 3;
        int qs = q ^ ((px >> 1) & 3);
        const u16* src = X + xplane + (((size_t)(row * 128 + px)) << 8) + ic0 + qs * 8;
        gload_lds16(src, csm + kh * 8192 + ((i * 256 + (t & ~63)) & 511) * 16);
      }
    }
  };

  bfrag8 af[4], xf[4];

#define READF(TAP)                                                            \
  {                                                                           \
    const int kh_ = (TAP) / 3, kw_ = (TAP) % 3, abuf_ = (TAP) & 1;            \
    _Pragma("unroll")                                                         \
    for (int m = 0; m < 4; ++m)                                               \
      af[m] = *reinterpret_cast<const bfrag8*>(csm + 24576 + abuf_ * 8192 +   \
                  ((och * 64 + m * 16 + lc) * 4 + (lq ^ sa)) * 16);           \
    _Pragma("unroll")                                                         \
    for (int n = 0; n < 4; ++n) {                                             \
      int S_ = pxh * 64 + n * 16 + lc + kw_;                                  \
      int col = S_ - 1;                                                       \
      col = col < 0 ? 0 : (col > 127 ? 127 : col);                            \
      xf[n] = *reinterpret_cast<const bfrag8*>(csm + kh_ * 8192 + col * 64 +  \
                  (lq ^ ((col >> 1) & 3)) * 16);                              \
    }                                                                         \
  }

#define FIXX(TAP)                                                             \
  {                                                                           \
    const int kw_ = (TAP) % 3;                                                \
    bfrag8 bz = {};                                                           \
    if (kw_ == 0) { if (pxh == 0 && lc == 0)  xf[0] = bz; }                   \
    if (kw_ == 2) { if (pxh == 1 && lc == 15) xf[3] = bz; }                   \
  }

#define DOMFMA()                                                              \
  {                                                                           \
    _Pragma("unroll")                                                         \
    for (int m = 0; m < 4; ++m)                                               \
      _Pragma("unroll")                                                       \
      for (int n = 0; n < 4; ++n)                                             \
        acc[m][n] = __builtin_amdgcn_mfma_f32_16x16x32_bf16(af[m], xf[n],     \
                                                            acc[m][n], 0, 0, 0); \
  }

  stageB(0);
  stageA(0, 0, 0);
  stageA(1, 1, 0);
  __syncthreads();

  for (int chunk = 0; chunk < 8; ++chunk) {
    const int ic0 = chunk * 32;
#pragma unroll
    for (int tap = 0; tap < 9; ++tap) {
      READF(tap);
      asm volatile("s_waitcnt lgkmcnt(0)" ::: "memory");
      __builtin_amdgcn_sched_barrier(0);
      FIXX(tap);
      if (tap >= 1 && tap <= 7) stageA(tap + 1, (tap + 1) & 1, ic0);
      __builtin_amdgcn_s_setprio(1);
      DOMFMA();
      __builtin_amdgcn_s_setprio(0);
      __builtin_amdgcn_sched_barrier(0);
      // drain OWN stage-A issues BEFORE the barrier -> barrier certifies all
      // waves' A(t+1) LDS writes landed (correctness invariant).
      asm volatile("s_waitcnt vmcnt(0)" ::: "memory");
      __builtin_amdgcn_sched_barrier(0);
      __builtin_amdgcn_s_barrier();
      __builtin_amdgcn_sched_barrier(0);
    }
    if (chunk < 7) {
      stageA(0, 0, ic0 + 32);
      stageA(1, 1, ic0 + 32);
      stageB(ic0 + 32);
      __syncthreads();                   // full drain once per chunk
    }
  }
#undef READF
#undef FIXX
#undef DOMFMA

  // ---- epilogue: acc -> Ost (bf16) + per-channel stat partials ----
  u16* Ost = (u16*)csm;                       // [128 px][136]
  float* sst = (float*)(csm + 34816);         // [2 pxh][2 s/ss][128 c]
  const int chb = och * 64 + lq * 4;          // local channel base
  const int pxb = pxh * 64 + lc;
  __syncthreads();                            // MFMA readers done before alias
#pragma unroll
  for (int m = 0; m < 4; ++m)
#pragma unroll
    for (int n = 0; n < 4; ++n) {
      u32 lo = (u32)f2bf(acc[m][n][0]) | ((u32)f2bf(acc[m][n][1]) << 16);
      u32 hi = (u32)f2bf(acc[m][n][2]) | ((u32)f2bf(acc[m][n][3]) << 16);
      uint2 pk = {lo, hi};
      *reinterpret_cast<uint2*>(&Ost[(pxb + n * 16) * 136 + chb + m * 16]) = pk;
    }
#pragma unroll
  for (int m = 0; m < 4; ++m)
#pragma unroll
    for (int r = 0; r < 4; ++r) {
      float s  = acc[m][0][r] + acc[m][1][r] + acc[m][2][r] + acc[m][3][r];
      float ss = acc[m][0][r] * acc[m][0][r] + acc[m][1][r] * acc[m][1][r] +
                 acc[m][2][r] * acc[m][2][r] + acc[m][3][r] * acc[m][3][r];
#pragma unroll
      for (int off = 1; off < 16; off <<= 1) {
        s  += __shfl_xor(s, off);
        ss += __shfl_xor(ss, off);
      }
      if (lc == 0) {
        int c = och * 64 + m * 16 + lq * 4 + r;   // local 0..127
        sst[pxh * 256 + c]       = s;
        sst[pxh * 256 + 128 + c] = ss;
      }
    }
  __syncthreads();

  if (t < 128) {
    float s  = sst[t]       + sst[256 + t];
    float ss = sst[128 + t] + sst[384 + t];
    size_t pb = (((size_t)bb * 128 + y0) * 256 + oc0 + t) * 2;
    part[pb]     = s;
    part[pb + 1] = ss;
  }
#pragma unroll
  for (int s8 = 0; s8 < 8; ++s8) {
    int pix = s8 * 16 + (t >> 4);
    int sub = t & 15;
    int4 v = *reinterpret_cast<const int4*>(&Ost[pix * 136 + sub * 8]);
    *reinterpret_cast<int4*>(Y + xplane + (((size_t)(y0 * 128 + pix)) << 8) + oc0 + sub * 8) = v;
  }

  // ---- optional raw patch-transpose emission: kT[b][ph][py][pw][c][px] ----
  if (kTout) {
    const size_t outbase = ((size_t)(bb * 16 + (y0 >> 3)) * 8 + (y0 & 7)) * 32768;
    const int half = t >> 7;          // 0/1
    const int cl = t & 127;           // local channel
#pragma unroll
    for (int i = 0; i < 8; ++i) {
      int pw = i * 2 + half;
      u16 o[8];
#pragma unroll
      for (int j = 0; j < 8; ++j) o[j] = Ost[(pw * 8 + j) * 136 + cl];
      *reinterpret_cast<int4*>(kTout + outbase + (size_t)(pw * 256 + oc0 + cl) * 8) =
          *reinterpret_cast<int4*>(o);
    }
  }
}

// ---------------------------------------------------------------------------
// Parallel stats reduce: one block per (group, batch[, which]).
// ---------------------------------------------------------------------------
__global__ __launch_bounds__(256) void gnstat2c(
    const float* __restrict__ part0, float* __restrict__ stat0,
    const float* __restrict__ part1, float* __restrict__ stat1)
{
  const float* part = (blockIdx.z == 0) ? part0 : part1;
  float* stat = (blockIdx.z == 0) ? stat0 : stat1;
  const int g = blockIdx.x, b = blockIdx.y;
  const int t = threadIdx.x;
  const int row = t >> 1, half = t & 1;
  const float* p = part + (((size_t)b * 128 + row) * 256 + g * 8 + half * 4) * 2;
  float4 v0 = *reinterpret_cast<const float4*>(p);
  float4 v1 = *reinterpret_cast<const float4*>(p + 4);
  float s  = v0.x + v0.z + v1.x + v1.z;
  float ss = v0.y + v0.w + v1.y + v1.w;
#pragma unroll
  for (int off = 1; off < 64; off <<= 1) {
    s  += __shfl_xor(s, off);
    ss += __shfl_xor(ss, off);
  }
  __shared__ float Ls[4], Lss[4];
  if ((t & 63) == 0) { Ls[t >> 6] = s; Lss[t >> 6] = ss; }
  __syncthreads();
  if (t == 0) {
    float S  = Ls[0] + Ls[1] + Ls[2] + Ls[3];
    float SS = Lss[0] + Lss[1] + Lss[2] + Lss[3];
    float mean = S * (1.f / 131072.f);
    float var  = SS * (1.f / 131072.f) - mean * mean;
    stat[b * 32 + g]       = mean;
    stat[256 + b * 32 + g] = rsqrtf(var + 1e-5f);
  }
}

// ---------------------------------------------------------------------------
// MFMA attention. q-norm fused on A-frag load (Bk rank-1 cancels in softmax);
// k-norm fused in the PV EPILOGUE (sum_j P = 1 exactly). PV reads RAW kT.
// ---------------------------------------------------------------------------
#define OST 272
__global__ __launch_bounds__(256, 3) void attn_mfma(
    const u16* __restrict__ yq, const u16* __restrict__ yk,
    const u16* __restrict__ kT, const u16* __restrict__ xl,
    const float* __restrict__ statq, const float* __restrict__ statk,
    const float* __restrict__ gqw, const float* __restrict__ gqb,
    const float* __restrict__ gkw, const float* __restrict__ gkb,
    u16* __restrict__ resid)
{
  __shared__ __attribute__((aligned(16))) u16 smem[64 * OST + 4 * 16 * 72];
  u16* Ost = smem;                       // [64][OST]
  u16* Pls = smem + 64 * OST;            // 4 x [16][72]

  const int n = blockIdx.x;
  const int b = n >> 8, ph = (n >> 4) & 15, pw = n & 15;
  const int t = threadIdx.x, l = t & 63, w = t >> 6;
  const int lc = l & 15, lg = l >> 4;

  auto tokaddr = [&](int tok) -> size_t {
    return (((size_t)(b * 128 + ph * 8 + (tok >> 3))) * 128 + pw * 8 + (tok & 7)) * 256;
  };

  // ---- QK^T; A-fragments normalized on the fly ----
  const size_t qa = tokaddr(16 * w + lc) + lg * 8;
  bfrag8 aF[8];
#pragma unroll
  for (int ks = 0; ks < 8; ++ks) {
    int c0 = lg * 8 + ks * 32;
    int g = ks * 4 + lg;
    float meanq = statq[b * 32 + g], rstdq = statq[256 + b * 32 + g];
    float rstdk = statk[256 + b * 32 + g];
    int4 v = *reinterpret_cast<const int4*>(yq + qa + ks * 32);
    float f[8]; unpack8(v, f);
    float4 w0 = *reinterpret_cast<const float4*>(gqw + c0);
    float4 w1 = *reinterpret_cast<const float4*>(gqw + c0 + 4);
    float4 b0 = *reinterpret_cast<const float4*>(gqb + c0);
    float4 b1 = *reinterpret_cast<const float4*>(gqb + c0 + 4);
    float4 k0 = *reinterpret_cast<const float4*>(gkw + c0);
    float4 k1 = *reinterpret_cast<const float4*>(gkw + c0 + 4);
    float ww[8] = {w0.x, w0.y, w0.z, w0.w, w1.x, w1.y, w1.z, w1.w};
    float bb[8] = {b0.x, b0.y, b0.z, b0.w, b1.x, b1.y, b1.z, b1.w};
    float kk[8] = {k0.x, k0.y, k0.z, k0.w, k1.x, k1.y, k1.z, k1.w};
    u16 o[8];
#pragma unroll
    for (int j = 0; j < 8; ++j) {
      float Aq = rstdq * ww[j];
      float Bq = bb[j] - meanq * Aq;
      float Ak = rstdk * kk[j];
      o[j] = f2bf((f[j] * Aq + Bq) * Ak);
    }
    aF[ks] = *reinterpret_cast<bfrag8*>(o);
  }

  f32x4 sacc[4];
#pragma unroll
  for (int nt = 0; nt < 4; ++nt) sacc[nt] = (f32x4){0.f, 0.f, 0.f, 0.f};

#pragma unroll
  for (int nt = 0; nt < 4; ++nt) {
    const size_t ka = tokaddr(nt * 16 + lc) + lg * 8;
    bfrag8 bF[8];
#pragma unroll
    for (int ks = 0; ks < 8; ++ks)
      bF[ks] = *reinterpret_cast<const bfrag8*>(yk + ka + ks * 32);
#pragma unroll
    for (int ks = 0; ks < 8; ++ks)
      sacc[nt] = __builtin_amdgcn_mfma_f32_16x16x32_bf16(aF[ks], bF[ks], sacc[nt], 0, 0, 0);
  }

  // ---- softmax over j; scale 1/sqrt(256) = 1/16 ----
  u16* Pw = Pls + w * (16 * 72);
#pragma unroll
  for (int r = 0; r < 4; ++r) {
    float m0 = fmaxf(fmaxf(sacc[0][r], sacc[1][r]), fmaxf(sacc[2][r], sacc[3][r]));
    m0 = fmaxf(m0, __shfl_xor(m0, 1));
    m0 = fmaxf(m0, __shfl_xor(m0, 2));
    m0 = fmaxf(m0, __shfl_xor(m0, 4));
    m0 = fmaxf(m0, __shfl_xor(m0, 8));
    float p0 = __expf((sacc[0][r] - m0) * 0.0625f);
    float p1 = __expf((sacc[1][r] - m0) * 0.0625f);
    float p2 = __expf((sacc[2][r] - m0) * 0.0625f);
    float p3 = __expf((sacc[3][r] - m0) * 0.0625f);
    float s0 = p0 + p1 + p2 + p3;
    s0 += __shfl_xor(s0, 1);
    s0 += __shfl_xor(s0, 2);
    s0 += __shfl_xor(s0, 4);
    s0 += __shfl_xor(s0, 8);
    float inv = 1.f / s0;
    int prow = (lg * 4 + r) * 72;
    Pw[prow + 0 * 16 + lc] = f2bf(p0 * inv);
    Pw[prow + 1 * 16 + lc] = f2bf(p1 * inv);
    Pw[prow + 2 * 16 + lc] = f2bf(p2 * inv);
    Pw[prow + 3 * 16 + lc] = f2bf(p3 * inv);
  }

  // ---- PV on RAW kT ----
  bfrag8 pA[2];
#pragma unroll
  for (int js = 0; js < 2; ++js)
    pA[js] = *reinterpret_cast<const bfrag8*>(Pw + lc * 72 + js * 32 + lg * 8);

  f32x4 pacc[16];
#pragma unroll
  for (int ct = 0; ct < 16; ++ct) pacc[ct] = (f32x4){0.f, 0.f, 0.f, 0.f};

#pragma unroll
  for (int ct = 0; ct < 16; ++ct) {
    bfrag8 vB[2];
#pragma unroll
    for (int js = 0; js < 2; ++js)
      vB[js] = *reinterpret_cast<const bfrag8*>(
          kT + ((size_t)((b * 16 + ph) * 8 + js * 4 + lg)) * 32768 +
          (size_t)(pw * 256 + ct * 16 + lc) * 8);
#pragma unroll
    for (int js = 0; js < 2; ++js)
      pacc[ct] = __builtin_amdgcn_mfma_f32_16x16x32_bf16(pA[js], vB[js], pacc[ct], 0, 0, 0);
  }

  // ---- epilogue: k-GN fold (O = A*Oraw + Bv, channel per-lane) -> LDS ----
#pragma unroll
  for (int ct = 0; ct < 16; ++ct) {
    int c = ct * 16 + lc;
    int g = c >> 3;
    float mean = statk[b * 32 + g], rstd = statk[256 + b * 32 + g];
    float A = rstd * gkw[c];
    float Bv = gkb[c] - mean * A;
#pragma unroll
    for (int r = 0; r < 4; ++r)
      Ost[(16 * w + lg * 4 + r) * OST + ct * 16 + lc] = f2bf(fmaf(pacc[ct][r], A, Bv));
  }
  __syncthreads();

#pragma unroll
  for (int s = 0; s < 8; ++s) {
    int px_ = t >> 5;
    int c16 = t & 31;
    size_t g = (((size_t)b * 128 + ph * 8 + s) * 128 + pw * 8 + px_) * 256 + c16 * 8;
    int4 o = *reinterpret_cast<const int4*>(&Ost[(s * 8 + px_) * OST + c16 * 8]);
    int4 r = *reinterpret_cast<const int4*>(xl + g);
    float fo[8], fr[8]; unpack8(o, fo); unpack8(r, fr);
    u16 pk[8];
#pragma unroll
    for (int j = 0; j < 8; ++j) pk[j] = f2bf(fo[j] + fr[j]);
    *reinterpret_cast<int4*>(resid + g) = *reinterpret_cast<int4*>(pk);
  }
}

// ---------------------------------------------------------------------------
// Final GN apply + NHWC bf16 -> NCHW fp32 transpose
// ---------------------------------------------------------------------------
__global__ __launch_bounds__(256) void gnapply_t(
    const u16* __restrict__ Y, const float* __restrict__ stat,
    const float* __restrict__ gw, const float* __restrict__ gb,
    float* __restrict__ out)
{
  const int row = blockIdx.x, b = blockIdx.y;
  const int t = threadIdx.x;
  const int px4 = (t & 31) * 4;
  const int c8 = (t >> 5) * 8;
#pragma unroll
  for (int p = 0; p < 4; ++p) {
    int c0 = p * 64 + c8;
    int g = c0 >> 3;
    float mean = stat[b * 32 + g], rstd = stat[256 + b * 32 + g];
    float A[8], Bv[8];
#pragma unroll
    for (int j = 0; j < 8; ++j) {
      A[j] = rstd * gw[c0 + j];
      Bv[j] = gb[c0 + j] - mean * A[j];
    }
    float vals[4][8];
#pragma unroll
    for (int e = 0; e < 4; ++e) {
      int4 v = *reinterpret_cast<const int4*>(Y + (((size_t)b * 128 + row) * 128 + px4 + e) * 256 + c0);
      float f[8]; unpack8(v, f);
#pragma unroll
      for (int j = 0; j < 8; ++j) vals[e][j] = fmaf(f[j], A[j], Bv[j]);
    }
#pragma unroll
    for (int j = 0; j < 8; ++j) {
      float4 o = {vals[0][j], vals[1][j], vals[2][j], vals[3][j]};
      *reinterpret_cast<float4*>(out + ((size_t)b * 256 + c0 + j) * 16384 + row * 128 + px4) = o;
    }
  }
}

// ---------------------------------------------------------------------------
extern "C" void kernel_launch(void* const* d_in, const int* in_sizes, int n_in,
                              void* d_out, int out_size, void* d_ws, size_t ws_size,
                              hipStream_t stream)
{
  const float* x_low  = (const float*)d_in[0];
  const float* x_high = (const float*)d_in[1];
  const float* w_q    = (const float*)d_in[2];
  const float* gq_w   = (const float*)d_in[3];
  const float* gq_b   = (const float*)d_in[4];
  const float* w_k    = (const float*)d_in[5];
  const float* gk_w   = (const float*)d_in[6];
  const float* gk_b   = (const float*)d_in[7];
  const float* w_o    = (const float*)d_in[8];
  const float* go_w   = (const float*)d_in[9];
  const float* go_b   = (const float*)d_in[10];
  float* out = (float*)d_out;

  char* ws = (char*)d_ws;
  const size_t slot = 67108864;           // 33.55M bf16
  u16* xl  = (u16*)(ws + 0 * slot);       // x_low bf16 NHWC ; later y3
  u16* xh  = (u16*)(ws + 1 * slot);       // x_high bf16 NHWC ; later resid
  u16* yq  = (u16*)(ws + 2 * slot);       // q conv out (raw)
  u16* yk  = (u16*)(ws + 3 * slot);       // k conv out (raw, QK^T B operand)
  u16* kT  = (u16*)(ws + 4 * slot);       // RAW k, patch-transposed (from conv2)
  u16* W2q = (u16*)(ws + 5 * slot);
  u16* W2k = W2q + 589824;
  u16* W2o = W2k + 589824;
  float* partq = (float*)(ws + 5 * slot + 3 * 1179648);
  float* partk = partq + 524288;
  float* parto = partk + 524288;
  float* statq = parto + 524288;
  float* statk = statq + 512;
  float* stato = statk + 512;

  wprep<<<dim3(576, 3), 256, 0, stream>>>(w_q, w_k, w_o, W2q, W2k, W2o);
  xpose<<<dim3(128, 8, 2), 256, 0, stream>>>(x_low, x_high, xl, xh);
  conv_mfma<<<2048, 256, 0, stream>>>(xl, W2q, yq, partq, nullptr);
  conv_mfma<<<2048, 256, 0, stream>>>(xh, W2k, yk, partk, kT);
  gnstat2c<<<dim3(32, 8, 2), 256, 0, stream>>>(partq, statq, partk, statk);
  attn_mfma<<<2048, 256, 0, stream>>>(yq, yk, kT, xl, statq, statk,
                                      gq_w, gq_b, gk_w, gk_b, xh);
  conv_mfma<<<2048, 256, 0, stream>>>(xh, W2o, xl, parto, nullptr);
  gnstat2c<<<dim3(32, 8, 1), 256, 0, stream>>>(parto, stato, parto, stato);
  gnapply_t<<<dim3(128, 8), 256, 0, stream>>>(xl, stato, go_w, go_b, out);
}

// Round 16
// 668.819 us; speedup vs baseline: 1.0464x; 1.0464x over previous
//
#include <hip/hip_runtime.h>

using u16 = unsigned short;
using u32 = unsigned int;

typedef short bfrag8 __attribute__((ext_vector_type(8)));   // 8 x bf16
typedef float f32x4  __attribute__((ext_vector_type(4)));

__device__ __forceinline__ void unpack8(const int4 v, float f[8]) {
  u32 a = (u32)v.x, b = (u32)v.y, c = (u32)v.z, d = (u32)v.w;
  f[0] = __uint_as_float(a << 16);
  f[1] = __uint_as_float(a & 0xffff0000u);
  f[2] = __uint_as_float(b << 16);
  f[3] = __uint_as_float(b & 0xffff0000u);
  f[4] = __uint_as_float(c << 16);
  f[5] = __uint_as_float(c & 0xffff0000u);
  f[6] = __uint_as_float(d << 16);
  f[7] = __uint_as_float(d & 0xffff0000u);
}

__device__ __forceinline__ u16 f2bf(float f) {
  u32 u = __float_as_uint(f);
  u32 r = u + 0x7fffu + ((u >> 16) & 1u);
  return (u16)(r >> 16);
}

__device__ __forceinline__ void gload_lds16(const void* g, void* l) {
  __builtin_amdgcn_global_load_lds(
      (const __attribute__((address_space(1))) void*)g,
      (__attribute__((address_space(3))) void*)l, 16, 0, 0);
}

// ---------------------------------------------------------------------------
// Weight prep: fp32 OIHW [256][256][3][3] -> bf16 [9 tap][256 oc][256 ic]
// ---------------------------------------------------------------------------
__global__ __launch_bounds__(256) void wprep(
    const float* __restrict__ wq, const float* __restrict__ wk, const float* __restrict__ wo,
    u16* __restrict__ dq, u16* __restrict__ dk, u16* __restrict__ dwo)
{
  const float* s = (blockIdx.y == 0) ? wq : (blockIdx.y == 1) ? wk : wo;
  u16* d = (blockIdx.y == 0) ? dq : (blockIdx.y == 1) ? dk : dwo;
  int id = blockIdx.x * 256 + threadIdx.x;
  int e = id * 4;                 // output element base: [tap][oc][ic]
  int tap = e >> 16;
  int rem = e & 65535;
  int oc = rem >> 8, ic = rem & 255;
  u16 o[4];
#pragma unroll
  for (int j = 0; j < 4; ++j)
    o[j] = f2bf(s[((size_t)oc * 256 + ic + j) * 9 + tap]);
  *reinterpret_cast<uint2*>(d + e) = *reinterpret_cast<uint2*>(o);
}

// ---------------------------------------------------------------------------
// Transpose-convert: fp32 NCHW -> bf16 NHWC.
// ---------------------------------------------------------------------------
__global__ __launch_bounds__(256) void xpose(
    const float* __restrict__ xa, const float* __restrict__ xb,
    u16* __restrict__ oa, u16* __restrict__ ob)
{
  const int row = blockIdx.x, b = blockIdx.y;
  const float* src = blockIdx.z ? xb : xa;
  u16* dst = blockIdx.z ? ob : oa;
  const int t = threadIdx.x;
  const int px4 = (t >> 3) * 4;     // 0..124
  const int c8 = (t & 7) * 8;       // 0..56
#pragma unroll
  for (int p = 0; p < 4; ++p) {
    int c0 = p * 64 + c8;
    float4 v[8];
#pragma unroll
    for (int j = 0; j < 8; ++j)
      v[j] = *reinterpret_cast<const float4*>(src + ((size_t)b * 256 + c0 + j) * 16384 + row * 128 + px4);
#pragma unroll
    for (int e = 0; e < 4; ++e) {
      u16 o[8];
      o[0] = f2bf(e==0?v[0].x:e==1?v[0].y:e==2?v[0].z:v[0].w);
      o[1] = f2bf(e==0?v[1].x:e==1?v[1].y:e==2?v[1].z:v[1].w);
      o[2] = f2bf(e==0?v[2].x:e==1?v[2].y:e==2?v[2].z:v[2].w);
      o[3] = f2bf(e==0?v[3].x:e==1?v[3].y:e==2?v[3].z:v[3].w);
      o[4] = f2bf(e==0?v[4].x:e==1?v[4].y:e==2?v[4].z:v[4].w);
      o[5] = f2bf(e==0?v[5].x:e==1?v[5].y:e==2?v[5].z:v[5].w);
      o[6] = f2bf(e==0?v[6].x:e==1?v[6].y:e==2?v[6].z:v[6].w);
      o[7] = f2bf(e==0?v[7].x:e==1?v[7].y:e==2?v[7].z:v[7].w);
      *reinterpret_cast<int4*>(dst + (((size_t)b * 128 + row) * 128 + px4 + e) * 256 + c0) =
          *reinterpret_cast<int4*>(o);
    }
  }
}

// ---------------------------------------------------------------------------
// Implicit-GEMM bf16 MFMA conv3x3 — R11-exact (verified 164 µs, VGPR 84).
// ---------------------------------------------------------------------------
__global__ __launch_bounds__(256, 3) void conv_mfma(
    const u16* __restrict__ X, const u16* __restrict__ W2, u16* __restrict__ Y,
    float* __restrict__ part, u16* __restrict__ kTout)
{
  __shared__ __attribute__((aligned(16))) char csm[49920];

  const int t = threadIdx.x;
  const int l = t & 63;
  const int wv = t >> 6;
  const int id = blockIdx.x;
  const int u = (id & 7) * 256 + (id >> 3);   // XCD-chunk swizzle (bijective, 2048)
  const int bb = u >> 8;
  const int y0 = (u >> 1) & 127;
  const int ocblk = u & 1;
  const int oc0 = ocblk * 128;
  const int och = wv >> 1, pxh = wv & 1;
  const int lc = l & 15, lq = l >> 4;
  const int sa = (lc >> 1) & 3;

  f32x4 acc[4][4];
#pragma unroll
  for (int m = 0; m < 4; ++m)
#pragma unroll
    for (int n = 0; n < 4; ++n) acc[m][n] = (f32x4){0.f, 0.f, 0.f, 0.f};

  const size_t xplane = (size_t)bb * (128 * 128 * 256);

  // upfront zeros: halo columns (cidx 0,129) + out-of-range kh planes
  {
    int4 z = {0, 0, 0, 0};
    if (t < 24) {
      int q = t & 3, sel = (t >> 2) & 1, kh = t >> 3;
      int cidx = sel ? 129 : 0;
      *reinterpret_cast<int4*>(csm + ((kh * 132 + cidx) * 4 + q) * 16) = z;
    }
    if (y0 == 0)
      for (int s = t; s < 528; s += 256) *reinterpret_cast<int4*>(csm + s * 16) = z;
    if (y0 == 127)
      for (int s = t; s < 528; s += 256) *reinterpret_cast<int4*>(csm + 16896 + s * 16) = z;
  }

  // A stage: 128 oc x 32 ic per tap. slot (oc,q) holds octet q ^ ((oc>>1)&3)
  auto stageA = [&](int tap, int buf, int ic0) {
#pragma unroll
    for (int i = 0; i < 2; ++i) {
      int idx = t + i * 256;
      int oc = idx >> 2, q = idx & 3;
      int qs = q ^ ((oc >> 1) & 3);
      const u16* src = W2 + (((size_t)(tap * 256 + oc0 + oc)) << 8) + ic0 + qs * 8;
      gload_lds16(src, csm + 25344 + buf * 8192 + (i * 256 + (t & ~63)) * 16);
    }
  };
  // B stage: slot cidx=px+1; slot q holds octet q ^ ((cidx>>1)&3)
  auto stageB = [&](int ic0) {
#pragma unroll
    for (int i = 0; i < 6; ++i) {
      int idx = t + i * 256;
      int kh = idx >> 9;
      int row = y0 - 1 + kh;
      if (row >= 0 && row < 128) {
        int px = (idx & 511) >> 2, q = idx & 3;
        int qs = q ^ (((px + 1) >> 1) & 3);
        const u16* src = X + xplane + (((size_t)(row * 128 + px)) << 8) + ic0 + qs * 8;
        gload_lds16(src, csm + 64 + kh * 256 + (i * 256 + (t & ~63)) * 16);
      }
    }
  };

  bfrag8 af0[4], xf0[4], af1[4], xf1[4];

#define READF(TAP, AF, XF)                                                    \
  {                                                                           \
    const int kh_ = (TAP) / 3, kw_ = (TAP) % 3, buf_ = (TAP) % 3;             \
    const int sb_ = ((lc + kw_) >> 1) & 3;                                    \
    _Pragma("unroll")                                                         \
    for (int m = 0; m < 4; ++m)                                               \
      AF[m] = *reinterpret_cast<const bfrag8*>(csm + 25344 + buf_ * 8192 +    \
                  ((och * 64 + m * 16 + lc) * 4 + (lq ^ sa)) * 16);           \
    _Pragma("unroll")                                                         \
    for (int n = 0; n < 4; ++n) {                                             \
      int S_ = pxh * 64 + n * 16 + lc + kw_;                                  \
      XF[n] = *reinterpret_cast<const bfrag8*>(csm + kh_ * 8448 + S_ * 64 +   \
                  (lq ^ sb_) * 16);                                           \
    }                                                                         \
  }

#define DOMFMA(AF, XF)                                                        \
  {                                                                           \
    _Pragma("unroll")                                                         \
    for (int m = 0; m < 4; ++m)                                               \
      _Pragma("unroll")                                                       \
      for (int n = 0; n < 4; ++n)                                             \
        acc[m][n] = __builtin_amdgcn_mfma_f32_16x16x32_bf16(AF[m], XF[n],     \
                                                            acc[m][n], 0, 0, 0); \
  }

  stageB(0);
  stageA(0, 0, 0);
  stageA(1, 1, 0);
  __syncthreads();

  for (int chunk = 0; chunk < 8; ++chunk) {
    const int ic0 = chunk * 32;
    READF(0, af0, xf0);
#pragma unroll
    for (int tap = 0; tap < 9; ++tap) {
      asm volatile("s_waitcnt lgkmcnt(0)" ::: "memory");
      __builtin_amdgcn_sched_barrier(0);
      if (tap <= 6) stageA(tap + 2, (tap + 2) % 3, ic0);
      if (tap <= 6) {
        asm volatile("s_waitcnt vmcnt(2)" ::: "memory");
      } else if (tap == 7) {
        asm volatile("s_waitcnt vmcnt(0)" ::: "memory");
      }
      __builtin_amdgcn_sched_barrier(0);
      __builtin_amdgcn_s_barrier();
      __builtin_amdgcn_sched_barrier(0);

      if (tap < 8) {
        if (tap & 1) { READF(tap + 1, af0, xf0); }
        else         { READF(tap + 1, af1, xf1); }
      }
      __builtin_amdgcn_s_setprio(1);
      if (tap & 1) { DOMFMA(af1, xf1); }
      else         { DOMFMA(af0, xf0); }
      __builtin_amdgcn_s_setprio(0);
    }
    if (chunk < 7) {
      stageA(0, 0, ic0 + 32);
      stageA(1, 1, ic0 + 32);
      stageB(ic0 + 32);
      __syncthreads();
    }
  }
#undef READF
#undef DOMFMA

  // ---- epilogue: acc -> Ost (bf16) + per-channel stat partials ----
  u16* Ost = (u16*)csm;                       // [128 px][136]
  float* sst = (float*)(csm + 34816);         // [2 pxh][2 s/ss][128 c]
  const int chb = och * 64 + lq * 4;          // local channel base
  const int pxb = pxh * 64 + lc;
  __syncthreads();                            // MFMA readers done before alias
#pragma unroll
  for (int m = 0; m < 4; ++m)
#pragma unroll
    for (int n = 0; n < 4; ++n) {
      u32 lo = (u32)f2bf(acc[m][n][0]) | ((u32)f2bf(acc[m][n][1]) << 16);
      u32 hi = (u32)f2bf(acc[m][n][2]) | ((u32)f2bf(acc[m][n][3]) << 16);
      uint2 pk = {lo, hi};
      *reinterpret_cast<uint2*>(&Ost[(pxb + n * 16) * 136 + chb + m * 16]) = pk;
    }
#pragma unroll
  for (int m = 0; m < 4; ++m)
#pragma unroll
    for (int r = 0; r < 4; ++r) {
      float s  = acc[m][0][r] + acc[m][1][r] + acc[m][2][r] + acc[m][3][r];
      float ss = acc[m][0][r] * acc[m][0][r] + acc[m][1][r] * acc[m][1][r] +
                 acc[m][2][r] * acc[m][2][r] + acc[m][3][r] * acc[m][3][r];
#pragma unroll
      for (int off = 1; off < 16; off <<= 1) {
        s  += __shfl_xor(s, off);
        ss += __shfl_xor(ss, off);
      }
      if (lc == 0) {
        int c = och * 64 + m * 16 + lq * 4 + r;   // local 0..127
        sst[pxh * 256 + c]       = s;
        sst[pxh * 256 + 128 + c] = ss;
      }
    }
  __syncthreads();

  if (t < 128) {
    float s  = sst[t]       + sst[256 + t];
    float ss = sst[128 + t] + sst[384 + t];
    size_t pb = (((size_t)bb * 128 + y0) * 256 + oc0 + t) * 2;
    part[pb]     = s;
    part[pb + 1] = ss;
  }
#pragma unroll
  for (int s8 = 0; s8 < 8; ++s8) {
    int pix = s8 * 16 + (t >> 4);
    int sub = t & 15;
    int4 v = *reinterpret_cast<const int4*>(&Ost[pix * 136 + sub * 8]);
    *reinterpret_cast<int4*>(Y + xplane + (((size_t)(y0 * 128 + pix)) << 8) + oc0 + sub * 8) = v;
  }

  // ---- optional raw patch-transpose emission: kT[b][ph][py][pw][c][px] ----
  if (kTout) {
    const size_t outbase = ((size_t)(bb * 16 + (y0 >> 3)) * 8 + (y0 & 7)) * 32768;
    const int half = t >> 7;          // 0/1
    const int cl = t & 127;           // local channel
#pragma unroll
    for (int i = 0; i < 8; ++i) {
      int pw = i * 2 + half;
      u16 o[8];
#pragma unroll
      for (int j = 0; j < 8; ++j) o[j] = Ost[(pw * 8 + j) * 136 + cl];
      *reinterpret_cast<int4*>(kTout + outbase + (size_t)(pw * 256 + oc0 + cl) * 8) =
          *reinterpret_cast<int4*>(o);
    }
  }
}

// ---------------------------------------------------------------------------
// Parallel stats reduce: one block per (group, batch[, which]).
// ---------------------------------------------------------------------------
__global__ __launch_bounds__(256) void gnstat2c(
    const float* __restrict__ part0, float* __restrict__ stat0,
    const float* __restrict__ part1, float* __restrict__ stat1)
{
  const float* part = (blockIdx.z == 0) ? part0 : part1;
  float* stat = (blockIdx.z == 0) ? stat0 : stat1;
  const int g = blockIdx.x, b = blockIdx.y;
  const int t = threadIdx.x;
  const int row = t >> 1, half = t & 1;
  const float* p = part + (((size_t)b * 128 + row) * 256 + g * 8 + half * 4) * 2;
  float4 v0 = *reinterpret_cast<const float4*>(p);
  float4 v1 = *reinterpret_cast<const float4*>(p + 4);
  float s  = v0.x + v0.z + v1.x + v1.z;
  float ss = v0.y + v0.w + v1.y + v1.w;
#pragma unroll
  for (int off = 1; off < 64; off <<= 1) {
    s  += __shfl_xor(s, off);
    ss += __shfl_xor(ss, off);
  }
  __shared__ float Ls[4], Lss[4];
  if ((t & 63) == 0) { Ls[t >> 6] = s; Lss[t >> 6] = ss; }
  __syncthreads();
  if (t == 0) {
    float S  = Ls[0] + Ls[1] + Ls[2] + Ls[3];
    float SS = Lss[0] + Lss[1] + Lss[2] + Lss[3];
    float mean = S * (1.f / 131072.f);
    float var  = SS * (1.f / 131072.f) - mean * mean;
    stat[b * 32 + g]       = mean;
    stat[256 + b * 32 + g] = rsqrtf(var + 1e-5f);
  }
}

// ---------------------------------------------------------------------------
// MFMA attention. q-norm fused on A-frag load (Bk rank-1 cancels in softmax);
// k-norm fused in the PV EPILOGUE (sum_j P = 1 exactly). PV reads RAW kT.
// ---------------------------------------------------------------------------
#define OST 272
__global__ __launch_bounds__(256, 3) void attn_mfma(
    const u16* __restrict__ yq, const u16* __restrict__ yk,
    const u16* __restrict__ kT, const u16* __restrict__ xl,
    const float* __restrict__ statq, const float* __restrict__ statk,
    const float* __restrict__ gqw, const float* __restrict__ gqb,
    const float* __restrict__ gkw, const float* __restrict__ gkb,
    u16* __restrict__ resid)
{
  __shared__ __attribute__((aligned(16))) u16 smem[64 * OST + 4 * 16 * 72];
  u16* Ost = smem;                       // [64][OST]
  u16* Pls = smem + 64 * OST;            // 4 x [16][72]

  const int n = blockIdx.x;
  const int b = n >> 8, ph = (n >> 4) & 15, pw = n & 15;
  const int t = threadIdx.x, l = t & 63, w = t >> 6;
  const int lc = l & 15, lg = l >> 4;

  auto tokaddr = [&](int tok) -> size_t {
    return (((size_t)(b * 128 + ph * 8 + (tok >> 3))) * 128 + pw * 8 + (tok & 7)) * 256;
  };

  // ---- QK^T; A-fragments normalized on the fly ----
  const size_t qa = tokaddr(16 * w + lc) + lg * 8;
  bfrag8 aF[8];
#pragma unroll
  for (int ks = 0; ks < 8; ++ks) {
    int c0 = lg * 8 + ks * 32;
    int g = ks * 4 + lg;
    float meanq = statq[b * 32 + g], rstdq = statq[256 + b * 32 + g];
    float rstdk = statk[256 + b * 32 + g];
    int4 v = *reinterpret_cast<const int4*>(yq + qa + ks * 32);
    float f[8]; unpack8(v, f);
    float4 w0 = *reinterpret_cast<const float4*>(gqw + c0);
    float4 w1 = *reinterpret_cast<const float4*>(gqw + c0 + 4);
    float4 b0 = *reinterpret_cast<const float4*>(gqb + c0);
    float4 b1 = *reinterpret_cast<const float4*>(gqb + c0 + 4);
    float4 k0 = *reinterpret_cast<const float4*>(gkw + c0);
    float4 k1 = *reinterpret_cast<const float4*>(gkw + c0 + 4);
    float ww[8] = {w0.x, w0.y, w0.z, w0.w, w1.x, w1.y, w1.z, w1.w};
    float bb[8] = {b0.x, b0.y, b0.z, b0.w, b1.x, b1.y, b1.z, b1.w};
    float kk[8] = {k0.x, k0.y, k0.z, k0.w, k1.x, k1.y, k1.z, k1.w};
    u16 o[8];
#pragma unroll
    for (int j = 0; j < 8; ++j) {
      float Aq = rstdq * ww[j];
      float Bq = bb[j] - meanq * Aq;
      float Ak = rstdk * kk[j];
      o[j] = f2bf((f[j] * Aq + Bq) * Ak);
    }
    aF[ks] = *reinterpret_cast<bfrag8*>(o);
  }

  f32x4 sacc[4];
#pragma unroll
  for (int nt = 0; nt < 4; ++nt) sacc[nt] = (f32x4){0.f, 0.f, 0.f, 0.f};

#pragma unroll
  for (int nt = 0; nt < 4; ++nt) {
    const size_t ka = tokaddr(nt * 16 + lc) + lg * 8;
    bfrag8 bF[8];
#pragma unroll
    for (int ks = 0; ks < 8; ++ks)
      bF[ks] = *reinterpret_cast<const bfrag8*>(yk + ka + ks * 32);
#pragma unroll
    for (int ks = 0; ks < 8; ++ks)
      sacc[nt] = __builtin_amdgcn_mfma_f32_16x16x32_bf16(aF[ks], bF[ks], sacc[nt], 0, 0, 0);
  }

  // ---- softmax over j; scale 1/sqrt(256) = 1/16 ----
  u16* Pw = Pls + w * (16 * 72);
#pragma unroll
  for (int r = 0; r < 4; ++r) {
    float m0 = fmaxf(fmaxf(sacc[0][r], sacc[1][r]), fmaxf(sacc[2][r], sacc[3][r]));
    m0 = fmaxf(m0, __shfl_xor(m0, 1));
    m0 = fmaxf(m0, __shfl_xor(m0, 2));
    m0 = fmaxf(m0, __shfl_xor(m0, 4));
    m0 = fmaxf(m0, __shfl_xor(m0, 8));
    float p0 = __expf((sacc[0][r] - m0) * 0.0625f);
    float p1 = __expf((sacc[1][r] - m0) * 0.0625f);
    float p2 = __expf((sacc[2][r] - m0) * 0.0625f);
    float p3 = __expf((sacc[3][r] - m0) * 0.0625f);
    float s0 = p0 + p1 + p2 + p3;
    s0 += __shfl_xor(s0, 1);
    s0 += __shfl_xor(s0, 2);
    s0 += __shfl_xor(s0, 4);
    s0 += __shfl_xor(s0, 8);
    float inv = 1.f / s0;
    int prow = (lg * 4 + r) * 72;
    Pw[prow + 0 * 16 + lc] = f2bf(p0 * inv);
    Pw[prow + 1 * 16 + lc] = f2bf(p1 * inv);
    Pw[prow + 2 * 16 + lc] = f2bf(p2 * inv);
    Pw[prow + 3 * 16 + lc] = f2bf(p3 * inv);
  }

  // ---- PV on RAW kT ----
  bfrag8 pA[2];
#pragma unroll
  for (int js = 0; js < 2; ++js)
    pA[js] = *reinterpret_cast<const bfrag8*>(Pw + lc * 72 + js * 32 + lg * 8);

  f32x4 pacc[16];
#pragma unroll
  for (int ct = 0; ct < 16; ++ct) pacc[ct] = (f32x4){0.f, 0.f, 0.f, 0.f};

#pragma unroll
  for (int ct = 0; ct < 16; ++ct) {
    bfrag8 vB[2];
#pragma unroll
    for (int js = 0; js < 2; ++js)
      vB[js] = *reinterpret_cast<const bfrag8*>(
          kT + ((size_t)((b * 16 + ph) * 8 + js * 4 + lg)) * 32768 +
          (size_t)(pw * 256 + ct * 16 + lc) * 8);
#pragma unroll
    for (int js = 0; js < 2; ++js)
      pacc[ct] = __builtin_amdgcn_mfma_f32_16x16x32_bf16(pA[js], vB[js], pacc[ct], 0, 0, 0);
  }

  // ---- epilogue: k-GN fold (O = A*Oraw + Bv, channel per-lane) -> LDS ----
#pragma unroll
  for (int ct = 0; ct < 16; ++ct) {
    int c = ct * 16 + lc;
    int g = c >> 3;
    float mean = statk[b * 32 + g], rstd = statk[256 + b * 32 + g];
    float A = rstd * gkw[c];
    float Bv = gkb[c] - mean * A;
#pragma unroll
    for (int r = 0; r < 4; ++r)
      Ost[(16 * w + lg * 4 + r) * OST + ct * 16 + lc] = f2bf(fmaf(pacc[ct][r], A, Bv));
  }
  __syncthreads();

#pragma unroll
  for (int s = 0; s < 8; ++s) {
    int px_ = t >> 5;
    int c16 = t & 31;
    size_t g = (((size_t)b * 128 + ph * 8 + s) * 128 + pw * 8 + px_) * 256 + c16 * 8;
    int4 o = *reinterpret_cast<const int4*>(&Ost[(s * 8 + px_) * OST + c16 * 8]);
    int4 r = *reinterpret_cast<const int4*>(xl + g);
    float fo[8], fr[8]; unpack8(o, fo); unpack8(r, fr);
    u16 pk[8];
#pragma unroll
    for (int j = 0; j < 8; ++j) pk[j] = f2bf(fo[j] + fr[j]);
    *reinterpret_cast<int4*>(resid + g) = *reinterpret_cast<int4*>(pk);
  }
}

// ---------------------------------------------------------------------------
// Final GN apply + NHWC bf16 -> NCHW fp32 transpose
// ---------------------------------------------------------------------------
__global__ __launch_bounds__(256) void gnapply_t(
    const u16* __restrict__ Y, const float* __restrict__ stat,
    const float* __restrict__ gw, const float* __restrict__ gb,
    float* __restrict__ out)
{
  const int row = blockIdx.x, b = blockIdx.y;
  const int t = threadIdx.x;
  const int px4 = (t & 31) * 4;
  const int c8 = (t >> 5) * 8;
#pragma unroll
  for (int p = 0; p < 4; ++p) {
    int c0 = p * 64 + c8;
    int g = c0 >> 3;
    float mean = stat[b * 32 + g], rstd = stat[256 + b * 32 + g];
    float A[8], Bv[8];
#pragma unroll
    for (int j = 0; j < 8; ++j) {
      A[j] = rstd * gw[c0 + j];
      Bv[j] = gb[c0 + j] - mean * A[j];
    }
    float vals[4][8];
#pragma unroll
    for (int e = 0; e < 4; ++e) {
      int4 v = *reinterpret_cast<const int4*>(Y + (((size_t)b * 128 + row) * 128 + px4 + e) * 256 + c0);
      float f[8]; unpack8(v, f);
#pragma unroll
      for (int j = 0; j < 8; ++j) vals[e][j] = fmaf(f[j], A[j], Bv[j]);
    }
#pragma unroll
    for (int j = 0; j < 8; ++j) {
      float4 o = {vals[0][j], vals[1][j], vals[2][j], vals[3][j]};
      *reinterpret_cast<float4*>(out + ((size_t)b * 256 + c0 + j) * 16384 + row * 128 + px4) = o;
    }
  }
}

// ---------------------------------------------------------------------------
extern "C" void kernel_launch(void* const* d_in, const int* in_sizes, int n_in,
                              void* d_out, int out_size, void* d_ws, size_t ws_size,
                              hipStream_t stream)
{
  const float* x_low  = (const float*)d_in[0];
  const float* x_high = (const float*)d_in[1];
  const float* w_q    = (const float*)d_in[2];
  const float* gq_w   = (const float*)d_in[3];
  const float* gq_b   = (const float*)d_in[4];
  const float* w_k    = (const float*)d_in[5];
  const float* gk_w   = (const float*)d_in[6];
  const float* gk_b   = (const float*)d_in[7];
  const float* w_o    = (const float*)d_in[8];
  const float* go_w   = (const float*)d_in[9];
  const float* go_b   = (const float*)d_in[10];
  float* out = (float*)d_out;

  char* ws = (char*)d_ws;
  const size_t slot = 67108864;           // 33.55M bf16
  u16* xl  = (u16*)(ws + 0 * slot);       // x_low bf16 NHWC ; later y3
  u16* xh  = (u16*)(ws + 1 * slot);       // x_high bf16 NHWC ; later resid
  u16* yq  = (u16*)(ws + 2 * slot);       // q conv out (raw)
  u16* yk  = (u16*)(ws + 3 * slot);       // k conv out (raw, QK^T B operand)
  u16* kT  = (u16*)(ws + 4 * slot);       // RAW k, patch-transposed (from conv2)
  u16* W2q = (u16*)(ws + 5 * slot);
  u16* W2k = W2q + 589824;
  u16* W2o = W2k + 589824;
  float* partq = (float*)(ws + 5 * slot + 3 * 1179648);
  float* partk = partq + 524288;
  float* parto = partk + 524288;
  float* statq = parto + 524288;
  float* statk = statq + 512;
  float* stato = statk + 512;

  wprep<<<dim3(576, 3), 256, 0, stream>>>(w_q, w_k, w_o, W2q, W2k, W2o);
  xpose<<<dim3(128, 8, 2), 256, 0, stream>>>(x_low, x_high, xl, xh);
  conv_mfma<<<2048, 256, 0, stream>>>(xl, W2q, yq, partq, nullptr);
  conv_mfma<<<2048, 256, 0, stream>>>(xh, W2k, yk, partk, kT);
  gnstat2c<<<dim3(32, 8, 2), 256, 0, stream>>>(partq, statq, partk, statk);
  attn_mfma<<<2048, 256, 0, stream>>>(yq, yk, kT, xl, statq, statk,
                                      gq_w, gq_b, gk_w, gk_b, xh);
  conv_mfma<<<2048, 256, 0, stream>>>(xh, W2o, xl, parto, nullptr);
  gnstat2c<<<dim3(32, 8, 1), 256, 0, stream>>>(parto, stato, parto, stato);
  gnapply_t<<<dim3(128, 8), 256, 0, stream>>>(xl, stato, go_w, go_b, out);
}

// Round 17
// 657.146 us; speedup vs baseline: 1.0650x; 1.0178x over previous
//
#include <hip/hip_runtime.h>

using u16 = unsigned short;
using u32 = unsigned int;

typedef short bfrag8 __attribute__((ext_vector_type(8)));   // 8 x bf16
typedef float f32x4  __attribute__((ext_vector_type(4)));

__device__ __forceinline__ void unpack8(const int4 v, float f[8]) {
  u32 a = (u32)v.x, b = (u32)v.y, c = (u32)v.z, d = (u32)v.w;
  f[0] = __uint_as_float(a << 16);
  f[1] = __uint_as_float(a & 0xffff0000u);
  f[2] = __uint_as_float(b << 16);
  f[3] = __uint_as_float(b & 0xffff0000u);
  f[4] = __uint_as_float(c << 16);
  f[5] = __uint_as_float(c & 0xffff0000u);
  f[6] = __uint_as_float(d << 16);
  f[7] = __uint_as_float(d & 0xffff0000u);
}

__device__ __forceinline__ u16 f2bf(float f) {
  u32 u = __float_as_uint(f);
  u32 r = u + 0x7fffu + ((u >> 16) & 1u);
  return (u16)(r >> 16);
}

__device__ __forceinline__ void gload_lds16(const void* g, void* l) {
  __builtin_amdgcn_global_load_lds(
      (const __attribute__((address_space(1))) void*)g,
      (__attribute__((address_space(3))) void*)l, 16, 0, 0);
}

// ---------------------------------------------------------------------------
// Weight prep: fp32 OIHW [256][256][3][3] -> bf16 [9 tap][256 oc][256 ic]
// ---------------------------------------------------------------------------
__global__ __launch_bounds__(256) void wprep(
    const float* __restrict__ wq, const float* __restrict__ wk, const float* __restrict__ wo,
    u16* __restrict__ dq, u16* __restrict__ dk, u16* __restrict__ dwo)
{
  const float* s = (blockIdx.y == 0) ? wq : (blockIdx.y == 1) ? wk : wo;
  u16* d = (blockIdx.y == 0) ? dq : (blockIdx.y == 1) ? dk : dwo;
  int id = blockIdx.x * 256 + threadIdx.x;
  int e = id * 4;                 // output element base: [tap][oc][ic]
  int tap = e >> 16;
  int rem = e & 65535;
  int oc = rem >> 8, ic = rem & 255;
  u16 o[4];
#pragma unroll
  for (int j = 0; j < 4; ++j)
    o[j] = f2bf(s[((size_t)oc * 256 + ic + j) * 9 + tap]);
  *reinterpret_cast<uint2*>(d + e) = *reinterpret_cast<uint2*>(o);
}

// ---------------------------------------------------------------------------
// Transpose-convert: fp32 NCHW -> bf16 NHWC.
// ---------------------------------------------------------------------------
__global__ __launch_bounds__(256) void xpose(
    const float* __restrict__ xa, const float* __restrict__ xb,
    u16* __restrict__ oa, u16* __restrict__ ob)
{
  const int row = blockIdx.x, b = blockIdx.y;
  const float* src = blockIdx.z ? xb : xa;
  u16* dst = blockIdx.z ? ob : oa;
  const int t = threadIdx.x;
  const int px4 = (t >> 3) * 4;     // 0..124
  const int c8 = (t & 7) * 8;       // 0..56
#pragma unroll
  for (int p = 0; p < 4; ++p) {
    int c0 = p * 64 + c8;
    float4 v[8];
#pragma unroll
    for (int j = 0; j < 8; ++j)
      v[j] = *reinterpret_cast<const float4*>(src + ((size_t)b * 256 + c0 + j) * 16384 + row * 128 + px4);
#pragma unroll
    for (int e = 0; e < 4; ++e) {
      u16 o[8];
      o[0] = f2bf(e==0?v[0].x:e==1?v[0].y:e==2?v[0].z:v[0].w);
      o[1] = f2bf(e==0?v[1].x:e==1?v[1].y:e==2?v[1].z:v[1].w);
      o[2] = f2bf(e==0?v[2].x:e==1?v[2].y:e==2?v[2].z:v[2].w);
      o[3] = f2bf(e==0?v[3].x:e==1?v[3].y:e==2?v[3].z:v[3].w);
      o[4] = f2bf(e==0?v[4].x:e==1?v[4].y:e==2?v[4].z:v[4].w);
      o[5] = f2bf(e==0?v[5].x:e==1?v[5].y:e==2?v[5].z:v[5].w);
      o[6] = f2bf(e==0?v[6].x:e==1?v[6].y:e==2?v[6].z:v[6].w);
      o[7] = f2bf(e==0?v[7].x:e==1?v[7].y:e==2?v[7].z:v[7].w);
      *reinterpret_cast<int4*>(dst + (((size_t)b * 128 + row) * 128 + px4 + e) * 256 + c0) =
          *reinterpret_cast<int4*>(o);
    }
  }
}

// ---------------------------------------------------------------------------
// Implicit-GEMM bf16 MFMA conv3x3 — R11/R13 inner loop verbatim (164 µs,
// VGPR 84). R17: TWO independent convs in ONE dispatch — blockIdx>>11
// selects pointer set (block-uniform, SGPR cselect), so conv2's blocks
// backfill conv1's drain-out residency round (zero-tail between them).
// ---------------------------------------------------------------------------
__global__ __launch_bounds__(256, 3) void conv_mfma(
    const u16* __restrict__ X0, const u16* __restrict__ W20, u16* __restrict__ Y0,
    float* __restrict__ part0, u16* __restrict__ kT0,
    const u16* __restrict__ X1, const u16* __restrict__ W21, u16* __restrict__ Y1,
    float* __restrict__ part1, u16* __restrict__ kT1)
{
  __shared__ __attribute__((aligned(16))) char csm[49920];

  const int t = threadIdx.x;
  const int l = t & 63;
  const int wv = t >> 6;
  const int which = blockIdx.x >> 11;         // 0: first conv, 1: second
  const u16* X  = which ? X1  : X0;
  const u16* W2 = which ? W21 : W20;
  u16* Y        = which ? Y1  : Y0;
  float* part   = which ? part1 : part0;
  u16* kTout    = which ? kT1 : kT0;
  const int id = blockIdx.x & 2047;
  const int u = (id & 7) * 256 + (id >> 3);   // XCD-chunk swizzle (bijective, 2048)
  const int bb = u >> 8;
  const int y0 = (u >> 1) & 127;
  const int ocblk = u & 1;
  const int oc0 = ocblk * 128;
  const int och = wv >> 1, pxh = wv & 1;
  const int lc = l & 15, lq = l >> 4;
  const int sa = (lc >> 1) & 3;

  f32x4 acc[4][4];
#pragma unroll
  for (int m = 0; m < 4; ++m)
#pragma unroll
    for (int n = 0; n < 4; ++n) acc[m][n] = (f32x4){0.f, 0.f, 0.f, 0.f};

  const size_t xplane = (size_t)bb * (128 * 128 * 256);

  // upfront zeros: halo columns (cidx 0,129) + out-of-range kh planes
  {
    int4 z = {0, 0, 0, 0};
    if (t < 24) {
      int q = t & 3, sel = (t >> 2) & 1, kh = t >> 3;
      int cidx = sel ? 129 : 0;
      *reinterpret_cast<int4*>(csm + ((kh * 132 + cidx) * 4 + q) * 16) = z;
    }
    if (y0 == 0)
      for (int s = t; s < 528; s += 256) *reinterpret_cast<int4*>(csm + s * 16) = z;
    if (y0 == 127)
      for (int s = t; s < 528; s += 256) *reinterpret_cast<int4*>(csm + 16896 + s * 16) = z;
  }

  // A stage: 128 oc x 32 ic per tap. slot (oc,q) holds octet q ^ ((oc>>1)&3)
  auto stageA = [&](int tap, int buf, int ic0) {
#pragma unroll
    for (int i = 0; i < 2; ++i) {
      int idx = t + i * 256;
      int oc = idx >> 2, q = idx & 3;
      int qs = q ^ ((oc >> 1) & 3);
      const u16* src = W2 + (((size_t)(tap * 256 + oc0 + oc)) << 8) + ic0 + qs * 8;
      gload_lds16(src, csm + 25344 + buf * 8192 + (i * 256 + (t & ~63)) * 16);
    }
  };
  // B stage: slot cidx=px+1; slot q holds octet q ^ ((cidx>>1)&3)
  auto stageB = [&](int ic0) {
#pragma unroll
    for (int i = 0; i < 6; ++i) {
      int idx = t + i * 256;
      int kh = idx >> 9;
      int row = y0 - 1 + kh;
      if (row >= 0 && row < 128) {
        int px = (idx & 511) >> 2, q = idx & 3;
        int qs = q ^ (((px + 1) >> 1) & 3);
        const u16* src = X + xplane + (((size_t)(row * 128 + px)) << 8) + ic0 + qs * 8;
        gload_lds16(src, csm + 64 + kh * 256 + (i * 256 + (t & ~63)) * 16);
      }
    }
  };

  bfrag8 af0[4], xf0[4], af1[4], xf1[4];

#define READF(TAP, AF, XF)                                                    \
  {                                                                           \
    const int kh_ = (TAP) / 3, kw_ = (TAP) % 3, buf_ = (TAP) % 3;             \
    const int sb_ = ((lc + kw_) >> 1) & 3;                                    \
    _Pragma("unroll")                                                         \
    for (int m = 0; m < 4; ++m)                                               \
      AF[m] = *reinterpret_cast<const bfrag8*>(csm + 25344 + buf_ * 8192 +    \
                  ((och * 64 + m * 16 + lc) * 4 + (lq ^ sa)) * 16);           \
    _Pragma("unroll")                                                         \
    for (int n = 0; n < 4; ++n) {                                             \
      int S_ = pxh * 64 + n * 16 + lc + kw_;                                  \
      XF[n] = *reinterpret_cast<const bfrag8*>(csm + kh_ * 8448 + S_ * 64 +   \
                  (lq ^ sb_) * 16);                                           \
    }                                                                         \
  }

#define DOMFMA(AF, XF)                                                        \
  {                                                                           \
    _Pragma("unroll")                                                         \
    for (int m = 0; m < 4; ++m)                                               \
      _Pragma("unroll")                                                       \
      for (int n = 0; n < 4; ++n)                                             \
        acc[m][n] = __builtin_amdgcn_mfma_f32_16x16x32_bf16(AF[m], XF[n],     \
                                                            acc[m][n], 0, 0, 0); \
  }

  stageB(0);
  stageA(0, 0, 0);
  stageA(1, 1, 0);
  __syncthreads();

  for (int chunk = 0; chunk < 8; ++chunk) {
    const int ic0 = chunk * 32;
    READF(0, af0, xf0);
#pragma unroll
    for (int tap = 0; tap < 9; ++tap) {
      asm volatile("s_waitcnt lgkmcnt(0)" ::: "memory");
      __builtin_amdgcn_sched_barrier(0);
      if (tap <= 6) stageA(tap + 2, (tap + 2) % 3, ic0);
      if (tap <= 6) {
        asm volatile("s_waitcnt vmcnt(2)" ::: "memory");
      } else if (tap == 7) {
        asm volatile("s_waitcnt vmcnt(0)" ::: "memory");
      }
      __builtin_amdgcn_sched_barrier(0);
      __builtin_amdgcn_s_barrier();
      __builtin_amdgcn_sched_barrier(0);

      if (tap < 8) {
        if (tap & 1) { READF(tap + 1, af0, xf0); }
        else         { READF(tap + 1, af1, xf1); }
      }
      __builtin_amdgcn_s_setprio(1);
      if (tap & 1) { DOMFMA(af1, xf1); }
      else         { DOMFMA(af0, xf0); }
      __builtin_amdgcn_s_setprio(0);
    }
    if (chunk < 7) {
      stageA(0, 0, ic0 + 32);
      stageA(1, 1, ic0 + 32);
      stageB(ic0 + 32);
      __syncthreads();
    }
  }
#undef READF
#undef DOMFMA

  // ---- epilogue: acc -> Ost (bf16) + per-channel stat partials ----
  u16* Ost = (u16*)csm;                       // [128 px][136]
  float* sst = (float*)(csm + 34816);         // [2 pxh][2 s/ss][128 c]
  const int chb = och * 64 + lq * 4;          // local channel base
  const int pxb = pxh * 64 + lc;
  __syncthreads();                            // MFMA readers done before alias
#pragma unroll
  for (int m = 0; m < 4; ++m)
#pragma unroll
    for (int n = 0; n < 4; ++n) {
      u32 lo = (u32)f2bf(acc[m][n][0]) | ((u32)f2bf(acc[m][n][1]) << 16);
      u32 hi = (u32)f2bf(acc[m][n][2]) | ((u32)f2bf(acc[m][n][3]) << 16);
      uint2 pk = {lo, hi};
      *reinterpret_cast<uint2*>(&Ost[(pxb + n * 16) * 136 + chb + m * 16]) = pk;
    }
#pragma unroll
  for (int m = 0; m < 4; ++m)
#pragma unroll
    for (int r = 0; r < 4; ++r) {
      float s  = acc[m][0][r] + acc[m][1][r] + acc[m][2][r] + acc[m][3][r];
      float ss = acc[m][0][r] * acc[m][0][r] + acc[m][1][r] * acc[m][1][r] +
                 acc[m][2][r] * acc[m][2][r] + acc[m][3][r] * acc[m][3][r];
#pragma unroll
      for (int off = 1; off < 16; off <<= 1) {
        s  += __shfl_xor(s, off);
        ss += __shfl_xor(ss, off);
      }
      if (lc == 0) {
        int c = och * 64 + m * 16 + lq * 4 + r;   // local 0..127
        sst[pxh * 256 + c]       = s;
        sst[pxh * 256 + 128 + c] = ss;
      }
    }
  __syncthreads();

  if (t < 128) {
    float s  = sst[t]       + sst[256 + t];
    float ss = sst[128 + t] + sst[384 + t];
    size_t pb = (((size_t)bb * 128 + y0) * 256 + oc0 + t) * 2;
    part[pb]     = s;
    part[pb + 1] = ss;
  }
#pragma unroll
  for (int s8 = 0; s8 < 8; ++s8) {
    int pix = s8 * 16 + (t >> 4);
    int sub = t & 15;
    int4 v = *reinterpret_cast<const int4*>(&Ost[pix * 136 + sub * 8]);
    *reinterpret_cast<int4*>(Y + xplane + (((size_t)(y0 * 128 + pix)) << 8) + oc0 + sub * 8) = v;
  }

  // ---- optional raw patch-transpose emission: kT[b][ph][py][pw][c][px] ----
  if (kTout) {
    const size_t outbase = ((size_t)(bb * 16 + (y0 >> 3)) * 8 + (y0 & 7)) * 32768;
    const int half = t >> 7;          // 0/1
    const int cl = t & 127;           // local channel
#pragma unroll
    for (int i = 0; i < 8; ++i) {
      int pw = i * 2 + half;
      u16 o[8];
#pragma unroll
      for (int j = 0; j < 8; ++j) o[j] = Ost[(pw * 8 + j) * 136 + cl];
      *reinterpret_cast<int4*>(kTout + outbase + (size_t)(pw * 256 + oc0 + cl) * 8) =
          *reinterpret_cast<int4*>(o);
    }
  }
}

// ---------------------------------------------------------------------------
// Parallel stats reduce: one block per (group, batch[, which]).
// ---------------------------------------------------------------------------
__global__ __launch_bounds__(256) void gnstat2c(
    const float* __restrict__ part0, float* __restrict__ stat0,
    const float* __restrict__ part1, float* __restrict__ stat1)
{
  const float* part = (blockIdx.z == 0) ? part0 : part1;
  float* stat = (blockIdx.z == 0) ? stat0 : stat1;
  const int g = blockIdx.x, b = blockIdx.y;
  const int t = threadIdx.x;
  const int row = t >> 1, half = t & 1;
  const float* p = part + (((size_t)b * 128 + row) * 256 + g * 8 + half * 4) * 2;
  float4 v0 = *reinterpret_cast<const float4*>(p);
  float4 v1 = *reinterpret_cast<const float4*>(p + 4);
  float s  = v0.x + v0.z + v1.x + v1.z;
  float ss = v0.y + v0.w + v1.y + v1.w;
#pragma unroll
  for (int off = 1; off < 64; off <<= 1) {
    s  += __shfl_xor(s, off);
    ss += __shfl_xor(ss, off);
  }
  __shared__ float Ls[4], Lss[4];
  if ((t & 63) == 0) { Ls[t >> 6] = s; Lss[t >> 6] = ss; }
  __syncthreads();
  if (t == 0) {
    float S  = Ls[0] + Ls[1] + Ls[2] + Ls[3];
    float SS = Lss[0] + Lss[1] + Lss[2] + Lss[3];
    float mean = S * (1.f / 131072.f);
    float var  = SS * (1.f / 131072.f) - mean * mean;
    stat[b * 32 + g]       = mean;
    stat[256 + b * 32 + g] = rsqrtf(var + 1e-5f);
  }
}

// ---------------------------------------------------------------------------
// MFMA attention. q-norm fused on A-frag load (Bk rank-1 cancels in softmax);
// k-norm fused in the PV EPILOGUE (sum_j P = 1 exactly). PV reads RAW kT.
// ---------------------------------------------------------------------------
#define OST 272
__global__ __launch_bounds__(256, 3) void attn_mfma(
    const u16* __restrict__ yq, const u16* __restrict__ yk,
    const u16* __restrict__ kT, const u16* __restrict__ xl,
    const float* __restrict__ statq, const float* __restrict__ statk,
    const float* __restrict__ gqw, const float* __restrict__ gqb,
    const float* __restrict__ gkw, const float* __restrict__ gkb,
    u16* __restrict__ resid)
{
  __shared__ __attribute__((aligned(16))) u16 smem[64 * OST + 4 * 16 * 72];
  u16* Ost = smem;                       // [64][OST]
  u16* Pls = smem + 64 * OST;            // 4 x [16][72]

  const int n = blockIdx.x;
  const int b = n >> 8, ph = (n >> 4) & 15, pw = n & 15;
  const int t = threadIdx.x, l = t & 63, w = t >> 6;
  const int lc = l & 15, lg = l >> 4;

  auto tokaddr = [&](int tok) -> size_t {
    return (((size_t)(b * 128 + ph * 8 + (tok >> 3))) * 128 + pw * 8 + (tok & 7)) * 256;
  };

  // ---- QK^T; A-fragments normalized on the fly ----
  const size_t qa = tokaddr(16 * w + lc) + lg * 8;
  bfrag8 aF[8];
#pragma unroll
  for (int ks = 0; ks < 8; ++ks) {
    int c0 = lg * 8 + ks * 32;
    int g = ks * 4 + lg;
    float meanq = statq[b * 32 + g], rstdq = statq[256 + b * 32 + g];
    float rstdk = statk[256 + b * 32 + g];
    int4 v = *reinterpret_cast<const int4*>(yq + qa + ks * 32);
    float f[8]; unpack8(v, f);
    float4 w0 = *reinterpret_cast<const float4*>(gqw + c0);
    float4 w1 = *reinterpret_cast<const float4*>(gqw + c0 + 4);
    float4 b0 = *reinterpret_cast<const float4*>(gqb + c0);
    float4 b1 = *reinterpret_cast<const float4*>(gqb + c0 + 4);
    float4 k0 = *reinterpret_cast<const float4*>(gkw + c0);
    float4 k1 = *reinterpret_cast<const float4*>(gkw + c0 + 4);
    float ww[8] = {w0.x, w0.y, w0.z, w0.w, w1.x, w1.y, w1.z, w1.w};
    float bb[8] = {b0.x, b0.y, b0.z, b0.w, b1.x, b1.y, b1.z, b1.w};
    float kk[8] = {k0.x, k0.y, k0.z, k0.w, k1.x, k1.y, k1.z, k1.w};
    u16 o[8];
#pragma unroll
    for (int j = 0; j < 8; ++j) {
      float Aq = rstdq * ww[j];
      float Bq = bb[j] - meanq * Aq;
      float Ak = rstdk * kk[j];
      o[j] = f2bf((f[j] * Aq + Bq) * Ak);
    }
    aF[ks] = *reinterpret_cast<bfrag8*>(o);
  }

  f32x4 sacc[4];
#pragma unroll
  for (int nt = 0; nt < 4; ++nt) sacc[nt] = (f32x4){0.f, 0.f, 0.f, 0.f};

#pragma unroll
  for (int nt = 0; nt < 4; ++nt) {
    const size_t ka = tokaddr(nt * 16 + lc) + lg * 8;
    bfrag8 bF[8];
#pragma unroll
    for (int ks = 0; ks < 8; ++ks)
      bF[ks] = *reinterpret_cast<const bfrag8*>(yk + ka + ks * 32);
#pragma unroll
    for (int ks = 0; ks < 8; ++ks)
      sacc[nt] = __builtin_amdgcn_mfma_f32_16x16x32_bf16(aF[ks], bF[ks], sacc[nt], 0, 0, 0);
  }

  // ---- softmax over j; scale 1/sqrt(256) = 1/16 ----
  u16* Pw = Pls + w * (16 * 72);
#pragma unroll
  for (int r = 0; r < 4; ++r) {
    float m0 = fmaxf(fmaxf(sacc[0][r], sacc[1][r]), fmaxf(sacc[2][r], sacc[3][r]));
    m0 = fmaxf(m0, __shfl_xor(m0, 1));
    m0 = fmaxf(m0, __shfl_xor(m0, 2));
    m0 = fmaxf(m0, __shfl_xor(m0, 4));
    m0 = fmaxf(m0, __shfl_xor(m0, 8));
    float p0 = __expf((sacc[0][r] - m0) * 0.0625f);
    float p1 = __expf((sacc[1][r] - m0) * 0.0625f);
    float p2 = __expf((sacc[2][r] - m0) * 0.0625f);
    float p3 = __expf((sacc[3][r] - m0) * 0.0625f);
    float s0 = p0 + p1 + p2 + p3;
    s0 += __shfl_xor(s0, 1);
    s0 += __shfl_xor(s0, 2);
    s0 += __shfl_xor(s0, 4);
    s0 += __shfl_xor(s0, 8);
    float inv = 1.f / s0;
    int prow = (lg * 4 + r) * 72;
    Pw[prow + 0 * 16 + lc] = f2bf(p0 * inv);
    Pw[prow + 1 * 16 + lc] = f2bf(p1 * inv);
    Pw[prow + 2 * 16 + lc] = f2bf(p2 * inv);
    Pw[prow + 3 * 16 + lc] = f2bf(p3 * inv);
  }

  // ---- PV on RAW kT ----
  bfrag8 pA[2];
#pragma unroll
  for (int js = 0; js < 2; ++js)
    pA[js] = *reinterpret_cast<const bfrag8*>(Pw + lc * 72 + js * 32 + lg * 8);

  f32x4 pacc[16];
#pragma unroll
  for (int ct = 0; ct < 16; ++ct) pacc[ct] = (f32x4){0.f, 0.f, 0.f, 0.f};

#pragma unroll
  for (int ct = 0; ct < 16; ++ct) {
    bfrag8 vB[2];
#pragma unroll
    for (int js = 0; js < 2; ++js)
      vB[js] = *reinterpret_cast<const bfrag8*>(
          kT + ((size_t)((b * 16 + ph) * 8 + js * 4 + lg)) * 32768 +
          (size_t)(pw * 256 + ct * 16 + lc) * 8);
#pragma unroll
    for (int js = 0; js < 2; ++js)
      pacc[ct] = __builtin_amdgcn_mfma_f32_16x16x32_bf16(pA[js], vB[js], pacc[ct], 0, 0, 0);
  }

  // ---- epilogue: k-GN fold (O = A*Oraw + Bv, channel per-lane) -> LDS ----
#pragma unroll
  for (int ct = 0; ct < 16; ++ct) {
    int c = ct * 16 + lc;
    int g = c >> 3;
    float mean = statk[b * 32 + g], rstd = statk[256 + b * 32 + g];
    float A = rstd * gkw[c];
    float Bv = gkb[c] - mean * A;
#pragma unroll
    for (int r = 0; r < 4; ++r)
      Ost[(16 * w + lg * 4 + r) * OST + ct * 16 + lc] = f2bf(fmaf(pacc[ct][r], A, Bv));
  }
  __syncthreads();

#pragma unroll
  for (int s = 0; s < 8; ++s) {
    int px_ = t >> 5;
    int c16 = t & 31;
    size_t g = (((size_t)b * 128 + ph * 8 + s) * 128 + pw * 8 + px_) * 256 + c16 * 8;
    int4 o = *reinterpret_cast<const int4*>(&Ost[(s * 8 + px_) * OST + c16 * 8]);
    int4 r = *reinterpret_cast<const int4*>(xl + g);
    float fo[8], fr[8]; unpack8(o, fo); unpack8(r, fr);
    u16 pk[8];
#pragma unroll
    for (int j = 0; j < 8; ++j) pk[j] = f2bf(fo[j] + fr[j]);
    *reinterpret_cast<int4*>(resid + g) = *reinterpret_cast<int4*>(pk);
  }
}

// ---------------------------------------------------------------------------
// Final GN apply + NHWC bf16 -> NCHW fp32 transpose
// ---------------------------------------------------------------------------
__global__ __launch_bounds__(256) void gnapply_t(
    const u16* __restrict__ Y, const float* __restrict__ stat,
    const float* __restrict__ gw, const float* __restrict__ gb,
    float* __restrict__ out)
{
  const int row = blockIdx.x, b = blockIdx.y;
  const int t = threadIdx.x;
  const int px4 = (t & 31) * 4;
  const int c8 = (t >> 5) * 8;
#pragma unroll
  for (int p = 0; p < 4; ++p) {
    int c0 = p * 64 + c8;
    int g = c0 >> 3;
    float mean = stat[b * 32 + g], rstd = stat[256 + b * 32 + g];
    float A[8], Bv[8];
#pragma unroll
    for (int j = 0; j < 8; ++j) {
      A[j] = rstd * gw[c0 + j];
      Bv[j] = gb[c0 + j] - mean * A[j];
    }
    float vals[4][8];
#pragma unroll
    for (int e = 0; e < 4; ++e) {
      int4 v = *reinterpret_cast<const int4*>(Y + (((size_t)b * 128 + row) * 128 + px4 + e) * 256 + c0);
      float f[8]; unpack8(v, f);
#pragma unroll
      for (int j = 0; j < 8; ++j) vals[e][j] = fmaf(f[j], A[j], Bv[j]);
    }
#pragma unroll
    for (int j = 0; j < 8; ++j) {
      float4 o = {vals[0][j], vals[1][j], vals[2][j], vals[3][j]};
      *reinterpret_cast<float4*>(out + ((size_t)b * 256 + c0 + j) * 16384 + row * 128 + px4) = o;
    }
  }
}

// ---------------------------------------------------------------------------
extern "C" void kernel_launch(void* const* d_in, const int* in_sizes, int n_in,
                              void* d_out, int out_size, void* d_ws, size_t ws_size,
                              hipStream_t stream)
{
  const float* x_low  = (const float*)d_in[0];
  const float* x_high = (const float*)d_in[1];
  const float* w_q    = (const float*)d_in[2];
  const float* gq_w   = (const float*)d_in[3];
  const float* gq_b   = (const float*)d_in[4];
  const float* w_k    = (const float*)d_in[5];
  const float* gk_w   = (const float*)d_in[6];
  const float* gk_b   = (const float*)d_in[7];
  const float* w_o    = (const float*)d_in[8];
  const float* go_w   = (const float*)d_in[9];
  const float* go_b   = (const float*)d_in[10];
  float* out = (float*)d_out;

  char* ws = (char*)d_ws;
  const size_t slot = 67108864;           // 33.55M bf16
  u16* xl  = (u16*)(ws + 0 * slot);       // x_low bf16 NHWC ; later y3
  u16* xh  = (u16*)(ws + 1 * slot);       // x_high bf16 NHWC ; later resid
  u16* yq  = (u16*)(ws + 2 * slot);       // q conv out (raw)
  u16* yk  = (u16*)(ws + 3 * slot);       // k conv out (raw, QK^T B operand)
  u16* kT  = (u16*)(ws + 4 * slot);       // RAW k, patch-transposed (from conv2)
  u16* W2q = (u16*)(ws + 5 * slot);
  u16* W2k = W2q + 589824;
  u16* W2o = W2k + 589824;
  float* partq = (float*)(ws + 5 * slot + 3 * 1179648);
  float* partk = partq + 524288;
  float* parto = partk + 524288;
  float* statq = parto + 524288;
  float* statk = statq + 512;
  float* stato = statk + 512;

  wprep<<<dim3(576, 3), 256, 0, stream>>>(w_q, w_k, w_o, W2q, W2k, W2o);
  xpose<<<dim3(128, 8, 2), 256, 0, stream>>>(x_low, x_high, xl, xh);
  // q-conv and k-conv fused into one 4096-block dispatch (independent work;
  // k-conv blocks backfill q-conv's residency tail)
  conv_mfma<<<4096, 256, 0, stream>>>(xl, W2q, yq, partq, nullptr,
                                      xh, W2k, yk, partk, kT);
  gnstat2c<<<dim3(32, 8, 2), 256, 0, stream>>>(partq, statq, partk, statk);
  attn_mfma<<<2048, 256, 0, stream>>>(yq, yk, kT, xl, statq, statk,
                                      gq_w, gq_b, gk_w, gk_b, xh);
  conv_mfma<<<2048, 256, 0, stream>>>(xh, W2o, xl, parto, nullptr,
                                      xh, W2o, xl, parto, nullptr);
  gnstat2c<<<dim3(32, 8, 1), 256, 0, stream>>>(parto, stato, parto, stato);
  gnapply_t<<<dim3(128, 8), 256, 0, stream>>>(xl, stato, go_w, go_b, out);
}